// Round 5
// baseline (570.315 us; speedup 1.0000x reference)
//
#include <hip/hip_runtime.h>
#include <hip/hip_bf16.h>
#include <cstdint>

#define D_DIM 768
#define BM 128
#define BN 256
// Pre-swizzled operand storage: per 32-row block R, per 64-byte k-chunk kc,
// a 2048-B block. byte layout: chunk*1024 + (h*32 + l31)*16 + b  holds
// X[R*32 + l31][kc*64 + h*32 + chunk*16 + b]  (the exact per-lane byte
// assignment of mfma_scale_f32_32x32x64_f8f6f4 operands, verified absmax=0
// in rounds 3-4 via the LDS path).
#define KCH (D_DIM / 64)        // 12 k-chunks
#define RBLK 24576              // 12 * 2048 bytes per 32-row block

typedef int   intx8    __attribute__((ext_vector_type(8)));
typedef float floatx16 __attribute__((ext_vector_type(16)));

#define SCALE_ONE 0x7F7F7F7F  // E8M0 127 = 2^0 in every byte

// ---- kernel 1: row L2 norm + normalize + cast fp8 + swizzled store ----------
// one wave per row; lane holds floats {4l..4l+4, 256+4l.., 512+4l..}.
// After fp8-convert each lane has 3 dwords at byte positions k=4l, 256+4l,
// 512+4l; all three share the same within-block offset, kc differs by +4/+8.

__global__ __launch_bounds__(256) void norm_cast_kernel(
    const float* __restrict__ EX, const float* __restrict__ EY,
    unsigned int* __restrict__ XO, unsigned int* __restrict__ YO, int Nx) {
  int row = blockIdx.x * 4 + (threadIdx.x >> 6);
  int lane = threadIdx.x & 63;
  const float* X = (row < Nx) ? EX : EY;
  unsigned int* Y = (row < Nx) ? XO : YO;
  int r = (row < Nx) ? row : (row - Nx);
  const float4* xr = (const float4*)(X + (size_t)r * D_DIM);
  float4 a = xr[lane];
  float4 b = xr[lane + 64];
  float4 c = xr[lane + 128];
  float ss = a.x*a.x + a.y*a.y + a.z*a.z + a.w*a.w
           + b.x*b.x + b.y*b.y + b.z*b.z + b.w*b.w
           + c.x*c.x + c.y*c.y + c.z*c.z + c.w*c.w;
  #pragma unroll
  for (int off = 32; off > 0; off >>= 1) ss += __shfl_xor(ss, off, 64);
  float s = 1.0f / fmaxf(sqrtf(ss), 1e-8f);
  int d0, d1, d2;
  d0 = __builtin_amdgcn_cvt_pk_fp8_f32(a.x * s, a.y * s, 0, false);
  d0 = __builtin_amdgcn_cvt_pk_fp8_f32(a.z * s, a.w * s, d0, true);
  d1 = __builtin_amdgcn_cvt_pk_fp8_f32(b.x * s, b.y * s, 0, false);
  d1 = __builtin_amdgcn_cvt_pk_fp8_f32(b.z * s, b.w * s, d1, true);
  d2 = __builtin_amdgcn_cvt_pk_fp8_f32(c.x * s, c.y * s, 0, false);
  d2 = __builtin_amdgcn_cvt_pk_fp8_f32(c.z * s, c.w * s, d2, true);
  // swizzled scatter: k=4*lane -> kc=lane>>4, chunk=(lane>>2)&1, h=(lane>>3)&1
  int rl = r & 31;
  unsigned int* dst = (unsigned int*)((char*)Y + (size_t)(r >> 5) * RBLK);
  int off = ((lane >> 4) * 2048) + (((lane >> 2) & 1) * 1024)
          + ((((lane >> 3) & 1) * 32 + rl) * 16) + ((lane & 3) * 4);
  dst[off >> 2]             = (unsigned int)d0;
  dst[(off + 8192) >> 2]    = (unsigned int)d1;   // kc += 4
  dst[(off + 16384) >> 2]   = (unsigned int)d2;   // kc += 8
}

// ---- kernel 2: MX-fp8 MFMA GEMM (S = A . B^T) fused with per-row max --------
// Block tile 128x256; 256 threads = 4 waves (2x2), wave tile 64x128 = 2x4
// grid of 32x32x64 mfma_scale. NO LDS in the K-loop: fragments load directly
// from the pre-swizzled operand blocks with coalesced dwordx4 (2 KB per frag
// set, served by L1/L2; working set 19 MB << L3). 12 ks-steps, double-
// buffered fragments, no barriers until epilogue. R4 lesson: LDS pipe
// (reads + deposit "conflicts" @16cyc/instr) cost ~4600 cyc/CU per 128-k
// vs 2208 cyc MFMA — removing LDS lifts the ceiling.

__device__ inline intx8 ldfragg(const char* p) {
  intx8 r;
  *(int4*)&r       = *(const int4*)p;
  *((int4*)&r + 1) = *(const int4*)(p + 1024);
  return r;
}

__global__ __launch_bounds__(256, 2) void gemm_max_kernel(
    const unsigned char* __restrict__ A,   // A_sw [Nx/32][12][2048]
    const unsigned char* __restrict__ B,   // B_sw [Ny/32][12][2048]
    float* __restrict__ partial,           // [ncb][Nx]
    int Nx) {
  __shared__ float red[2][BM];

  const int tid  = threadIdx.x;
  const int wave = tid >> 6;
  const int lane = tid & 63;
  const int wm = wave >> 1;        // 0..1: row half (64 rows)
  const int wn = wave & 1;         // 0..1: col half (128 cols)
  const int l31 = lane & 31;
  const int h   = lane >> 5;

  floatx16 acc[2][4];
  #pragma unroll
  for (int mt = 0; mt < 2; ++mt)
    #pragma unroll
    for (int nt = 0; nt < 4; ++nt)
      acc[mt][nt] = (floatx16)(0.f);

  // fragment base pointers (lane-strided within a 2 KB block)
  const char* aB[2];
  const char* bB[4];
  #pragma unroll
  for (int mt = 0; mt < 2; ++mt)
    aB[mt] = (const char*)A + (size_t)(blockIdx.x * 4 + wm * 2 + mt) * RBLK + lane * 16;
  #pragma unroll
  for (int nt = 0; nt < 4; ++nt)
    bB[nt] = (const char*)B + (size_t)(blockIdx.y * 8 + wn * 4 + nt) * RBLK + lane * 16;

  intx8 af[2][2], bf[2][4];
  #pragma unroll
  for (int mt = 0; mt < 2; ++mt) af[0][mt] = ldfragg(aB[mt]);
  #pragma unroll
  for (int nt = 0; nt < 4; ++nt) bf[0][nt] = ldfragg(bB[nt]);

  #pragma unroll
  for (int ks = 0; ks < KCH; ++ks) {
    const int cur = ks & 1, nxt = cur ^ 1;
    if (ks + 1 < KCH) {
      #pragma unroll
      for (int mt = 0; mt < 2; ++mt) af[nxt][mt] = ldfragg(aB[mt] + (ks + 1) * 2048);
      #pragma unroll
      for (int nt = 0; nt < 4; ++nt) bf[nxt][nt] = ldfragg(bB[nt] + (ks + 1) * 2048);
    }
    #pragma unroll
    for (int nt = 0; nt < 4; ++nt) {
      acc[0][nt] = __builtin_amdgcn_mfma_scale_f32_32x32x64_f8f6f4(
          af[cur][0], bf[cur][nt], acc[0][nt], 0, 0, 0, SCALE_ONE, 0, SCALE_ONE);
      acc[1][nt] = __builtin_amdgcn_mfma_scale_f32_32x32x64_f8f6f4(
          af[cur][1], bf[cur][nt], acc[1][nt], 0, 0, 0, SCALE_ONE, 0, SCALE_ONE);
    }
  }

  // epilogue: per-row max over this block's 256 columns.
  // C/D (32x32): col = l31 (+nt*32 + wn*128), row = (reg&3)+8*(reg>>2)+4*h (+mt*32+wm*64)
  #pragma unroll
  for (int mt = 0; mt < 2; ++mt) {
    #pragma unroll
    for (int reg = 0; reg < 16; ++reg) {
      float v = fmaxf(fmaxf(acc[mt][0][reg], acc[mt][1][reg]),
                      fmaxf(acc[mt][2][reg], acc[mt][3][reg]));
      #pragma unroll
      for (int off = 1; off < 32; off <<= 1)
        v = fmaxf(v, __shfl_xor(v, off, 64));
      if (l31 == 0) {
        int r = wm * 64 + mt * 32 + (reg & 3) + 8 * (reg >> 2) + 4 * h;
        red[wn][r] = v;
      }
    }
  }
  __syncthreads();
  if (tid < BM) {
    float m = fmaxf(red[0][tid], red[1][tid]);
    partial[(size_t)blockIdx.y * Nx + blockIdx.x * BM + tid] = m;
  }
}

// ---- kernel 3: row max over column blocks + halfnormal transform + block sum

__global__ __launch_bounds__(256) void rowmax_kernel(
    const float* __restrict__ partial, float* __restrict__ bsum, int Nx, int ncb) {
  __shared__ float sdata[4];
  int r = blockIdx.x * blockDim.x + threadIdx.x;
  float m = -1e30f;
  for (int cb = 0; cb < ncb; ++cb)
    m = fmaxf(m, partial[(size_t)cb * Nx + r]);
  float x = 1.0f - m;
  const float logc = -0.22579135264472744f;  // 0.5*log(2/pi), sigma=1
  float l = logc - 0.5f * x * x;
  float t = -__expf(l) * l;
  #pragma unroll
  for (int off = 32; off > 0; off >>= 1) t += __shfl_xor(t, off, 64);
  int wave = threadIdx.x >> 6;
  int lane = threadIdx.x & 63;
  if (lane == 0) sdata[wave] = t;
  __syncthreads();
  if (threadIdx.x == 0)
    bsum[blockIdx.x] = sdata[0] + sdata[1] + sdata[2] + sdata[3];
}

// ---- kernel 4: final sum of block partials -> out[0], out[1] ----------------

__global__ __launch_bounds__(64) void final_kernel(
    const float* __restrict__ bsum, float* __restrict__ out, int nb) {
  int lane = threadIdx.x;
  float s = (lane < nb) ? bsum[lane] : 0.f;
  #pragma unroll
  for (int off = 32; off > 0; off >>= 1) s += __shfl_xor(s, off, 64);
  if (lane == 0) { out[0] = s; out[1] = s; }
}

// ---- launch -----------------------------------------------------------------

extern "C" void kernel_launch(void* const* d_in, const int* in_sizes, int n_in,
                              void* d_out, int out_size, void* d_ws, size_t ws_size,
                              hipStream_t stream) {
  const float* ex = (const float*)d_in[0];
  const float* ey = (const float*)d_in[1];
  const int Nx = in_sizes[0] / D_DIM;   // 8192
  const int Ny = in_sizes[1] / D_DIM;   // 16384
  const int ncb = Ny / BN;              // 64

  char* ws = (char*)d_ws;
  unsigned char* exn = (unsigned char*)ws;                                   // Nx/32 * 24576
  unsigned char* eyn = exn + (size_t)(Nx / 32) * RBLK;                       // Ny/32 * 24576
  float* partial = (float*)(eyn + (size_t)(Ny / 32) * RBLK);                 // ncb*Nx f32
  float* bsum    = partial + (size_t)ncb * Nx;                               // 32 f32

  norm_cast_kernel<<<(Nx + Ny) / 4, 256, 0, stream>>>(
      ex, ey, (unsigned int*)exn, (unsigned int*)eyn, Nx);
  gemm_max_kernel<<<dim3(Nx / BM, Ny / BN), 256, 0, stream>>>(exn, eyn, partial, Nx);
  rowmax_kernel<<<Nx / 256, 256, 0, stream>>>(partial, bsum, Nx, ncb);
  final_kernel<<<1, 64, 0, stream>>>(bsum, (float*)d_out, Nx / 256);
}